// Round 1
// baseline (476.772 us; speedup 1.0000x reference)
//
#include <hip/hip_runtime.h>

#define K_TOP 5000
#define NB_BUCKET 8192
#define BUCKET_SHIFT 13   // idx>>13 < 6104 for n=50M

// ---- order-preserving float<->key mapping -------------------------------
__device__ __forceinline__ unsigned f2key(float f) {
    unsigned u = __float_as_uint(f);
    return (u & 0x80000000u) ? ~u : (u | 0x80000000u);
}
__device__ __forceinline__ float key2f(unsigned k) {
    unsigned u = (k & 0x80000000u) ? (k ^ 0x80000000u) : ~k;
    return __uint_as_float(u);
}

// ---- pass 1: 2048-bin histogram of key>>21 ------------------------------
__global__ __launch_bounds__(256) void k_hist(const float4* __restrict__ x4, long n4,
                                              int tail, const float* __restrict__ x,
                                              unsigned* __restrict__ hist) {
    __shared__ unsigned lh[2048];
    for (int i = threadIdx.x; i < 2048; i += blockDim.x) lh[i] = 0;
    __syncthreads();
    long gid = (long)blockIdx.x * blockDim.x + threadIdx.x;
    long stride = (long)gridDim.x * blockDim.x;
    for (long i = gid; i < n4; i += stride) {
        float4 v = x4[i];
        atomicAdd(&lh[f2key(v.x) >> 21], 1u);
        atomicAdd(&lh[f2key(v.y) >> 21], 1u);
        atomicAdd(&lh[f2key(v.z) >> 21], 1u);
        atomicAdd(&lh[f2key(v.w) >> 21], 1u);
    }
    if (gid < tail) atomicAdd(&lh[f2key(x[n4 * 4 + gid]) >> 21], 1u);
    __syncthreads();
    for (int i = threadIdx.x; i < 2048; i += blockDim.x) {
        unsigned c = lh[i];
        if (c) atomicAdd(&hist[i], c);
    }
}

// ---- find threshold bin: L = b<<21 --------------------------------------
// ctrl layout: [0]=candCount [1]=selCount [2]=L [3]=T [4]=idxCut
__global__ __launch_bounds__(1024) void k_findbin(const unsigned* __restrict__ hist,
                                                  unsigned* __restrict__ ctrl) {
    __shared__ unsigned lh[2048];
    __shared__ unsigned gsum[64];
    for (int i = threadIdx.x; i < 2048; i += blockDim.x) lh[i] = hist[i];
    __syncthreads();
    int t = threadIdx.x;
    if (t < 64) {
        unsigned s = 0;
        for (int j = 0; j < 32; j++) s += lh[t * 32 + j];
        gsum[t] = s;
    }
    __syncthreads();
    if (t == 0) {
        unsigned target = K_TOP, cum = 0;
        int g = 63;
        for (; g > 0; g--) { if (cum + gsum[g] >= target) break; cum += gsum[g]; }
        int b = g * 32 + 31;
        for (; b > g * 32; b--) { if (cum + lh[b] >= target) break; cum += lh[b]; }
        ctrl[2] = ((unsigned)b) << 21;
    }
}

// ---- pass 2: compact candidates (key >= L) ------------------------------
__global__ __launch_bounds__(256) void k_compact(const float4* __restrict__ x4, long n4,
                                                 int tail, const float* __restrict__ x,
                                                 const unsigned* __restrict__ ctrl,
                                                 unsigned* __restrict__ candCount,
                                                 unsigned* __restrict__ candKey,
                                                 unsigned* __restrict__ candIdx,
                                                 unsigned capC) {
    if (capC == 0) return;
    unsigned L = ctrl[2];
    long gid = (long)blockIdx.x * blockDim.x + threadIdx.x;
    long stride = (long)gridDim.x * blockDim.x;
    for (long i = gid; i < n4; i += stride) {
        float4 v = x4[i];
        unsigned base = (unsigned)(i * 4);
        unsigned k0 = f2key(v.x), k1 = f2key(v.y), k2 = f2key(v.z), k3 = f2key(v.w);
        if (k0 >= L) { unsigned p = atomicAdd(candCount, 1u); if (p < capC) { candKey[p] = k0; candIdx[p] = base; } }
        if (k1 >= L) { unsigned p = atomicAdd(candCount, 1u); if (p < capC) { candKey[p] = k1; candIdx[p] = base + 1; } }
        if (k2 >= L) { unsigned p = atomicAdd(candCount, 1u); if (p < capC) { candKey[p] = k2; candIdx[p] = base + 2; } }
        if (k3 >= L) { unsigned p = atomicAdd(candCount, 1u); if (p < capC) { candKey[p] = k3; candIdx[p] = base + 3; } }
    }
    if (gid < tail) {
        unsigned k = f2key(x[n4 * 4 + gid]);
        if (k >= L) {
            unsigned p = atomicAdd(candCount, 1u);
            if (p < capC) { candKey[p] = k; candIdx[p] = (unsigned)(n4 * 4 + gid); }
        }
    }
}

// ---- in-block scans over LDS histograms ---------------------------------
__device__ void zero_hist(unsigned* h, int nb) {
    for (int i = threadIdx.x; i < nb; i += blockDim.x) h[i] = 0;
}
// descending: find b s.t. count(bins>b) < target <= count(bins>=b); res[0]=b res[1]=target-count_above
__device__ void scan_desc(unsigned* h, int nb, unsigned target, unsigned* gsum, unsigned* res) {
    int t = threadIdx.x;
    int ng = (nb >= 64) ? 64 : 1;
    int gsz = nb / ng;
    if (t < ng) {
        unsigned s = 0;
        for (int j = 0; j < gsz; j++) s += h[t * gsz + j];
        gsum[t] = s;
    }
    __syncthreads();
    if (t == 0) {
        unsigned cum = 0;
        int g = ng - 1;
        for (; g > 0; g--) { if (cum + gsum[g] >= target) break; cum += gsum[g]; }
        int b = g * gsz + gsz - 1;
        for (; b > g * gsz; b--) { if (cum + h[b] >= target) break; cum += h[b]; }
        res[0] = (unsigned)b; res[1] = target - cum;
    }
    __syncthreads();
}
// ascending: find b s.t. count(bins<b) < target <= count(bins<=b)
__device__ void scan_asc(unsigned* h, int nb, unsigned target, unsigned* gsum, unsigned* res) {
    int t = threadIdx.x;
    int ng = (nb >= 64) ? 64 : 1;
    int gsz = nb / ng;
    if (t < ng) {
        unsigned s = 0;
        for (int j = 0; j < gsz; j++) s += h[t * gsz + j];
        gsum[t] = s;
    }
    __syncthreads();
    if (t == 0) {
        unsigned cum = 0;
        int g = 0;
        for (; g < ng - 1; g++) { if (cum + gsum[g] >= target) break; cum += gsum[g]; }
        int b = g * gsz;
        for (; b < g * gsz + gsz - 1; b++) { if (cum + h[b] >= target) break; cum += h[b]; }
        res[0] = (unsigned)b; res[1] = target - cum;
    }
    __syncthreads();
}

// ---- exact threshold key T + tie-break index cutoff ---------------------
__global__ __launch_bounds__(1024) void k_select(const unsigned* __restrict__ candKey,
                                                 const unsigned* __restrict__ candIdx,
                                                 unsigned* __restrict__ ctrl, unsigned capC) {
    __shared__ unsigned h[2048];
    __shared__ unsigned gsum[64];
    __shared__ unsigned res[2];
    __shared__ unsigned scnt;
    int t = threadIdx.x;
    unsigned Nc = ctrl[0];
    if (Nc > capC) Nc = capC;

    // round 0: key bits 31..21
    zero_hist(h, 2048); __syncthreads();
    for (unsigned i = t; i < Nc; i += blockDim.x) atomicAdd(&h[candKey[i] >> 21], 1u);
    __syncthreads();
    scan_desc(h, 2048, K_TOP, gsum, res);
    unsigned b0 = res[0], rem = res[1];

    // round 1: bits 20..10
    zero_hist(h, 2048); __syncthreads();
    for (unsigned i = t; i < Nc; i += blockDim.x) {
        unsigned k = candKey[i];
        if ((k >> 21) == b0) atomicAdd(&h[(k >> 10) & 0x7FFu], 1u);
    }
    __syncthreads();
    scan_desc(h, 2048, rem, gsum, res);
    unsigned pfx = (b0 << 11) | res[0];
    rem = res[1];

    // round 2: bits 9..0
    zero_hist(h, 1024); __syncthreads();
    for (unsigned i = t; i < Nc; i += blockDim.x) {
        unsigned k = candKey[i];
        if ((k >> 10) == pfx) atomicAdd(&h[k & 0x3FFu], 1u);
    }
    __syncthreads();
    scan_desc(h, 1024, rem, gsum, res);
    unsigned T = (pfx << 10) | res[0];
    unsigned R = res[1];   // need R elements equal to T, smallest indices

    if (t == 0) scnt = 0;
    __syncthreads();
    for (unsigned i = t; i < Nc; i += blockDim.x)
        if (candKey[i] == T) atomicAdd(&scnt, 1u);
    __syncthreads();
    unsigned cntEq = scnt;
    unsigned idxCut = 0xFFFFFFFFu;
    if (cntEq != R) {  // uniform branch: select R-th smallest idx among key==T
        zero_hist(h, 2048); __syncthreads();
        for (unsigned i = t; i < Nc; i += blockDim.x)
            if (candKey[i] == T) atomicAdd(&h[candIdx[i] >> 15], 1u);
        __syncthreads();
        scan_asc(h, 2048, R, gsum, res);
        unsigned bA = res[0], remI = res[1];
        zero_hist(h, 1024); __syncthreads();
        for (unsigned i = t; i < Nc; i += blockDim.x)
            if (candKey[i] == T && (candIdx[i] >> 15) == bA)
                atomicAdd(&h[(candIdx[i] >> 5) & 0x3FFu], 1u);
        __syncthreads();
        scan_asc(h, 1024, remI, gsum, res);
        unsigned pfi = (bA << 10) | res[0];
        remI = res[1];
        zero_hist(h, 32); __syncthreads();
        for (unsigned i = t; i < Nc; i += blockDim.x)
            if (candKey[i] == T && (candIdx[i] >> 5) == pfi)
                atomicAdd(&h[candIdx[i] & 31u], 1u);
        __syncthreads();
        scan_asc(h, 32, remI, gsum, res);
        idxCut = (pfi << 5) | res[0];
    }
    if (t == 0) { ctrl[3] = T; ctrl[4] = idxCut; }
}

// ---- compact exactly-K selected + bucket counts -------------------------
__global__ __launch_bounds__(256) void k_sel_compact(const unsigned* __restrict__ candKey,
                                                     const unsigned* __restrict__ candIdx,
                                                     unsigned* __restrict__ ctrl, unsigned capC,
                                                     unsigned* __restrict__ selKey,
                                                     unsigned* __restrict__ selIdx,
                                                     unsigned* __restrict__ bucketCnt) {
    unsigned Nc = ctrl[0];
    if (Nc > capC) Nc = capC;
    unsigned T = ctrl[3], idxCut = ctrl[4];
    unsigned gid = blockIdx.x * blockDim.x + threadIdx.x;
    unsigned stride = gridDim.x * blockDim.x;
    for (unsigned i = gid; i < Nc; i += stride) {
        unsigned k = candKey[i];
        unsigned idx = candIdx[i];
        if (k > T || (k == T && idx <= idxCut)) {
            unsigned p = atomicAdd(&ctrl[1], 1u);
            if (p < K_TOP) {
                selKey[p] = k;
                selIdx[p] = idx;
                atomicAdd(&bucketCnt[idx >> BUCKET_SHIFT], 1u);
            }
        }
    }
}

// ---- exclusive scan of 8192 bucket counts (1 block, 1024 thr) -----------
__global__ __launch_bounds__(1024) void k_bucket_scan(const unsigned* __restrict__ bucketCnt,
                                                      unsigned* __restrict__ bucketStart) {
    __shared__ unsigned part[1024];
    int t = threadIdx.x;
    unsigned loc[8];
    unsigned s = 0;
    for (int j = 0; j < 8; j++) { loc[j] = bucketCnt[t * 8 + j]; s += loc[j]; }
    part[t] = s;
    __syncthreads();
    if (t == 0) {
        unsigned run = 0;
        for (int i = 0; i < 1024; i++) { unsigned v = part[i]; part[i] = run; run += v; }
    }
    __syncthreads();
    unsigned run = part[t];
    for (int j = 0; j < 8; j++) { bucketStart[t * 8 + j] = run; run += loc[j]; }
}

// ---- scatter selected into bucket-sorted order --------------------------
__global__ __launch_bounds__(256) void k_scatter(const unsigned* __restrict__ selKey,
                                                 const unsigned* __restrict__ selIdx,
                                                 const unsigned* __restrict__ ctrl,
                                                 const unsigned* __restrict__ bucketStart,
                                                 unsigned* __restrict__ bucketCursor,
                                                 unsigned* __restrict__ selKeyS,
                                                 unsigned* __restrict__ selIdxS) {
    unsigned n = ctrl[1];
    if (n > K_TOP) n = K_TOP;
    unsigned g = blockIdx.x * blockDim.x + threadIdx.x;
    if (g >= n) return;
    unsigned idx = selIdx[g];
    unsigned b = idx >> BUCKET_SHIFT;
    unsigned p = bucketStart[b] + atomicAdd(&bucketCursor[b], 1u);
    if (p < K_TOP) { selKeyS[p] = selKey[g]; selIdxS[p] = idx; }
}

// ---- per-bucket tiny sort by idx + emit values --------------------------
__global__ __launch_bounds__(256) void k_finalize(const unsigned* __restrict__ bucketCnt,
                                                  const unsigned* __restrict__ bucketStart,
                                                  unsigned* __restrict__ selKeyS,
                                                  unsigned* __restrict__ selIdxS,
                                                  float* __restrict__ out) {
    int b = blockIdx.x * blockDim.x + threadIdx.x;
    if (b >= NB_BUCKET) return;
    unsigned n = bucketCnt[b];
    if (n == 0) return;
    unsigned s = bucketStart[b];
    for (unsigned i = 0; i < n; i++) {
        unsigned mi = i;
        unsigned mv = selIdxS[s + i];
        for (unsigned j = i + 1; j < n; j++) {
            unsigned v = selIdxS[s + j];
            if (v < mv) { mv = v; mi = j; }
        }
        if (mi != i) {
            unsigned ti = selIdxS[s + i]; selIdxS[s + i] = selIdxS[s + mi]; selIdxS[s + mi] = ti;
            unsigned tk = selKeyS[s + i]; selKeyS[s + i] = selKeyS[s + mi]; selKeyS[s + mi] = tk;
        }
        out[s + i] = key2f(selKeyS[s + i]);
    }
}

// ---- host launch --------------------------------------------------------
// ws layout (u32 words):
//   [0..2047]        hist1
//   [2048..2055]     ctrl: candCount, selCount, L, T, idxCut, spare
//   [2056..10247]    bucketCnt[8192]
//   [10248..18439]   bucketStart[8192]
//   [18440..26631]   bucketCursor[8192]      <-- memset covers [0..26631]
//   [26632..31631]   selKey[5000]
//   [31632..36631]   selIdx[5000]
//   [36632..41631]   selKeyS[5000]
//   [41632..46631]   selIdxS[5000]
//   [49152...]       candKey[capC] ++ candIdx[capC]
extern "C" void kernel_launch(void* const* d_in, const int* in_sizes, int n_in,
                              void* d_out, int out_size, void* d_ws, size_t ws_size,
                              hipStream_t stream) {
    const float* x = (const float*)d_in[0];
    long n = in_sizes[0];
    float* out = (float*)d_out;
    unsigned* w = (unsigned*)d_ws;

    unsigned* hist1        = w;
    unsigned* ctrl         = w + 2048;
    unsigned* bucketCnt    = w + 2056;
    unsigned* bucketStart  = w + 10248;
    unsigned* bucketCursor = w + 18440;
    unsigned* selKey       = w + 26632;
    unsigned* selIdx       = w + 31632;
    unsigned* selKeyS      = w + 36632;
    unsigned* selIdxS      = w + 41632;
    const size_t CAND_BASE = 49152;
    size_t words = ws_size / 4;
    unsigned capC = 0;
    if (words > CAND_BASE + 64) {
        size_t c = (words - CAND_BASE) / 2;
        if (c > (size_t)(8u << 20)) c = (size_t)(8u << 20);
        capC = (unsigned)c;
    }
    unsigned* candKey = w + CAND_BASE;
    unsigned* candIdx = candKey + capC;

    hipMemsetAsync(d_ws, 0, 26632u * 4u, stream);

    long n4 = n / 4;
    int tail = (int)(n & 3);
    k_hist<<<1024, 256, 0, stream>>>((const float4*)x, n4, tail, x, hist1);
    k_findbin<<<1, 1024, 0, stream>>>(hist1, ctrl);
    k_compact<<<1024, 256, 0, stream>>>((const float4*)x, n4, tail, x, ctrl,
                                        &ctrl[0], candKey, candIdx, capC);
    k_select<<<1, 1024, 0, stream>>>(candKey, candIdx, ctrl, capC);
    k_sel_compact<<<64, 256, 0, stream>>>(candKey, candIdx, ctrl, capC,
                                          selKey, selIdx, bucketCnt);
    k_bucket_scan<<<1, 1024, 0, stream>>>(bucketCnt, bucketStart);
    k_scatter<<<(K_TOP + 255) / 256, 256, 0, stream>>>(selKey, selIdx, ctrl, bucketStart,
                                                       bucketCursor, selKeyS, selIdxS);
    k_finalize<<<(NB_BUCKET + 255) / 256, 256, 0, stream>>>(bucketCnt, bucketStart,
                                                            selKeyS, selIdxS, out);
}

// Round 2
// 370.197 us; speedup vs baseline: 1.2879x; 1.2879x over previous
//
#include <hip/hip_runtime.h>

#define K_TOP 5000
#define NBIN 2048
#define CAND_LDS 1024
#define NB_BUCKET 4096
#define TARGET_SAMPLED 94u   // ~12000 true candidates at 1/128 sampling

// ---- order-preserving float<->key mapping -------------------------------
__device__ __forceinline__ unsigned f2key(float f) {
    unsigned u = __float_as_uint(f);
    return (u & 0x80000000u) ? ~u : (u | 0x80000000u);
}
__device__ __forceinline__ float key2f(unsigned k) {
    unsigned u = (k & 0x80000000u) ? (k ^ 0x80000000u) : ~k;
    return __uint_as_float(u);
}

// ---- sampled histogram: 64 consecutive float4 of every 8192 (1/128) -----
__global__ __launch_bounds__(256) void k_sample(const float4* __restrict__ x4, long n4,
                                                unsigned* __restrict__ hist) {
    __shared__ unsigned lh[NBIN];
    for (int i = threadIdx.x; i < NBIN; i += 256) lh[i] = 0;
    __syncthreads();
    int wave = threadIdx.x >> 6;
    int lane = threadIdx.x & 63;
    long gw = (long)blockIdx.x * 4 + wave;
    long totW = (long)gridDim.x * 4;
    long nChunk = (n4 + 8191) / 8192;
    for (long c = gw; c < nChunk; c += totW) {
        long i = c * 8192 + lane;
        if (i < n4) {
            float4 v = x4[i];
            atomicAdd(&lh[f2key(v.x) >> 21], 1u);
            atomicAdd(&lh[f2key(v.y) >> 21], 1u);
            atomicAdd(&lh[f2key(v.z) >> 21], 1u);
            atomicAdd(&lh[f2key(v.w) >> 21], 1u);
        }
    }
    __syncthreads();
    for (int i = threadIdx.x; i < NBIN; i += 256) {
        unsigned c = lh[i];
        if (c) atomicAdd(&hist[i], c);
    }
}

// ---- pick conservative threshold L from sampled histogram ---------------
// ctrl: [0]=candCount [1]=L
__global__ __launch_bounds__(256) void k_findbin(const unsigned* __restrict__ hist,
                                                 unsigned* __restrict__ ctrl) {
    __shared__ unsigned lh[NBIN];
    __shared__ unsigned gs[64];
    for (int i = threadIdx.x; i < NBIN; i += 256) lh[i] = hist[i];
    __syncthreads();
    int t = threadIdx.x;
    if (t < 64) {
        unsigned s = 0;
        for (int j = 0; j < 32; j++) s += lh[t * 32 + j];
        gs[t] = s;
    }
    __syncthreads();
    if (t == 0) {
        unsigned cum = 0;
        int g = 63;
        for (; g > 0; g--) { if (cum + gs[g] >= TARGET_SAMPLED) break; cum += gs[g]; }
        int b = g * 32 + 31;
        for (; b > g * 32; b--) { if (cum + lh[b] >= TARGET_SAMPLED) break; cum += lh[b]; }
        ctrl[1] = ((unsigned)b) << 21;
    }
}

// ---- full pass: compact candidates (key >= L), LDS-staged ---------------
__global__ __launch_bounds__(256) void k_compact(const float4* __restrict__ x4, long n4,
                                                 long n, const float* __restrict__ x,
                                                 unsigned* __restrict__ ctrl,
                                                 unsigned* __restrict__ candKey,
                                                 unsigned* __restrict__ candIdx,
                                                 unsigned capC) {
    __shared__ unsigned sKey[CAND_LDS], sIdx[CAND_LDS];
    __shared__ unsigned sCnt, sBase;
    if (threadIdx.x == 0) sCnt = 0;
    __syncthreads();
    unsigned L = ctrl[1];
    unsigned* candCount = &ctrl[0];

    // tail (n % 4) handled by block 0
    int tail = (int)(n & 3);
    if (blockIdx.x == 0 && threadIdx.x < tail) {
        unsigned k = f2key(x[n4 * 4 + threadIdx.x]);
        if (k >= L) {
            unsigned p = atomicAdd(&sCnt, 1u);
            if (p < CAND_LDS) { sKey[p] = k; sIdx[p] = (unsigned)(n4 * 4 + threadIdx.x); }
            else {
                unsigned q = atomicAdd(candCount, 1u);
                if (q < capC) { candKey[q] = k; candIdx[q] = (unsigned)(n4 * 4 + threadIdx.x); }
            }
        }
    }

    long tiles = (n4 + 1023) >> 10;
    for (long tile = blockIdx.x; tile < tiles; tile += gridDim.x) {
        long base = tile << 10;
        long i0 = base + threadIdx.x;
        long i1 = i0 + 256, i2 = i0 + 512, i3 = i0 + 768;
        bool in0 = i0 < n4, in1 = i1 < n4, in2 = i2 < n4, in3 = i3 < n4;
        float4 v0, v1, v2, v3;
        if (in0) v0 = x4[i0];
        if (in1) v1 = x4[i1];
        if (in2) v2 = x4[i2];
        if (in3) v3 = x4[i3];
#define PROC(vv, inb, ii)                                                            \
        if (inb) {                                                                   \
            unsigned kk, bb = (unsigned)((ii) * 4);                                  \
            kk = f2key((vv).x);                                                      \
            if (kk >= L) { unsigned p = atomicAdd(&sCnt, 1u);                        \
                if (p < CAND_LDS) { sKey[p] = kk; sIdx[p] = bb; }                    \
                else { unsigned q = atomicAdd(candCount, 1u);                        \
                       if (q < capC) { candKey[q] = kk; candIdx[q] = bb; } } }       \
            kk = f2key((vv).y);                                                      \
            if (kk >= L) { unsigned p = atomicAdd(&sCnt, 1u);                        \
                if (p < CAND_LDS) { sKey[p] = kk; sIdx[p] = bb + 1; }                \
                else { unsigned q = atomicAdd(candCount, 1u);                        \
                       if (q < capC) { candKey[q] = kk; candIdx[q] = bb + 1; } } }   \
            kk = f2key((vv).z);                                                      \
            if (kk >= L) { unsigned p = atomicAdd(&sCnt, 1u);                        \
                if (p < CAND_LDS) { sKey[p] = kk; sIdx[p] = bb + 2; }                \
                else { unsigned q = atomicAdd(candCount, 1u);                        \
                       if (q < capC) { candKey[q] = kk; candIdx[q] = bb + 2; } } }   \
            kk = f2key((vv).w);                                                      \
            if (kk >= L) { unsigned p = atomicAdd(&sCnt, 1u);                        \
                if (p < CAND_LDS) { sKey[p] = kk; sIdx[p] = bb + 3; }                \
                else { unsigned q = atomicAdd(candCount, 1u);                        \
                       if (q < capC) { candKey[q] = kk; candIdx[q] = bb + 3; } } }   \
        }
        PROC(v0, in0, i0)
        PROC(v1, in1, i1)
        PROC(v2, in2, i2)
        PROC(v3, in3, i3)
#undef PROC
    }
    __syncthreads();
    unsigned cnt = sCnt; if (cnt > CAND_LDS) cnt = CAND_LDS;
    if (threadIdx.x == 0) sBase = atomicAdd(candCount, cnt);
    __syncthreads();
    unsigned bp = sBase;
    for (unsigned i = threadIdx.x; i < cnt; i += 256) {
        unsigned q = bp + i;
        if (q < capC) { candKey[q] = sKey[i]; candIdx[q] = sIdx[i]; }
    }
}

// ---- fused finalize: exact T + tie-break + bucket sort + emit -----------
__global__ __launch_bounds__(1024) void k_final(const unsigned* __restrict__ candKey,
                                                const unsigned* __restrict__ candIdx,
                                                unsigned* __restrict__ ctrl, unsigned capC,
                                                unsigned* __restrict__ selKey,
                                                unsigned* __restrict__ selIdx,
                                                unsigned* __restrict__ selKeyS,
                                                unsigned* __restrict__ selIdxS,
                                                float* __restrict__ out, long n, int bshift) {
    __shared__ unsigned h[NB_BUCKET * 2];   // 32 KB
    __shared__ unsigned part[1024];
    __shared__ unsigned part2[32];
    __shared__ unsigned res[2];
    __shared__ unsigned sScalar;
    const int t = threadIdx.x;
    unsigned Nc = ctrl[0]; if (Nc > capC) Nc = capC;
    unsigned L = ctrl[1];

    // --- max key ---
    unsigned mk = 0;
    for (unsigned i = t; i < Nc; i += 1024) { unsigned k = candKey[i]; if (k > mk) mk = k; }
    part[t] = mk;
    __syncthreads();
    if (t < 32) { unsigned m = 0; for (int j = 0; j < 32; j++) { unsigned v = part[t * 32 + j]; if (v > m) m = v; } part2[t] = m; }
    __syncthreads();
    if (t == 0) { unsigned m = 0; for (int j = 0; j < 32; j++) if (part2[j] > m) m = part2[j]; sScalar = m; }
    __syncthreads();
    unsigned maxK = sScalar;

    // --- iterative radix-select: K_TOP-th from top ---
    unsigned lo = L, target = K_TOP;
    unsigned range = maxK - lo;
    int shift = 0;
    while ((range >> shift) >= NBIN) shift++;
    for (;;) {
        int nb = (int)(range >> shift) + 1;
        for (int i = t; i < nb; i += 1024) h[i] = 0;
        __syncthreads();
        for (unsigned i = t; i < Nc; i += 1024) {
            unsigned d = candKey[i] - lo;
            if (d <= range) atomicAdd(&h[d >> shift], 1u);
        }
        __syncthreads();
        int ng = (nb + 31) >> 5;
        if (t < ng) {
            unsigned s = 0; int b0 = t * 32, e = b0 + 32; if (e > nb) e = nb;
            for (int j = b0; j < e; j++) s += h[j];
            part[t] = s;
        }
        __syncthreads();
        if (t == 0) {
            unsigned cum = 0; int g = ng - 1;
            for (; g > 0; g--) { if (cum + part[g] >= target) break; cum += part[g]; }
            int hi2 = g * 32 + 31; if (hi2 > nb - 1) hi2 = nb - 1;
            int b = hi2;
            for (; b > g * 32; b--) { if (cum + h[b] >= target) break; cum += h[b]; }
            res[0] = (unsigned)b; res[1] = target - cum;
        }
        __syncthreads();
        lo += res[0] << shift; target = res[1];
        if (shift == 0) break;
        range = (1u << shift) - 1;
        shift = (shift > 11) ? shift - 11 : 0;
    }
    unsigned T = lo, R = target;

    // --- count equal keys ---
    if (t == 0) sScalar = 0;
    __syncthreads();
    for (unsigned i = t; i < Nc; i += 1024)
        if (candKey[i] == T) atomicAdd(&sScalar, 1u);
    __syncthreads();
    unsigned cntEq = sScalar;
    unsigned idxCut = 0xFFFFFFFFu;
    if (cntEq != R) {  // uniform branch
        unsigned lo2 = 0, tgt = R;
        unsigned range2 = (unsigned)(n - 1);
        int sh = 0;
        while ((range2 >> sh) >= NBIN) sh++;
        for (;;) {
            int nb = (int)(range2 >> sh) + 1;
            for (int i = t; i < nb; i += 1024) h[i] = 0;
            __syncthreads();
            for (unsigned i = t; i < Nc; i += 1024)
                if (candKey[i] == T) {
                    unsigned d = candIdx[i] - lo2;
                    if (d <= range2) atomicAdd(&h[d >> sh], 1u);
                }
            __syncthreads();
            int ng = (nb + 31) >> 5;
            if (t < ng) {
                unsigned s = 0; int b0 = t * 32, e = b0 + 32; if (e > nb) e = nb;
                for (int j = b0; j < e; j++) s += h[j];
                part[t] = s;
            }
            __syncthreads();
            if (t == 0) {
                unsigned cum = 0; int g = 0;
                for (; g < ng - 1; g++) { if (cum + part[g] >= tgt) break; cum += part[g]; }
                int b = g * 32; int hi2 = g * 32 + 31; if (hi2 > nb - 1) hi2 = nb - 1;
                for (; b < hi2; b++) { if (cum + h[b] >= tgt) break; cum += h[b]; }
                res[0] = (unsigned)b; res[1] = tgt - cum;
            }
            __syncthreads();
            lo2 += res[0] << sh; tgt = res[1];
            if (sh == 0) break;
            range2 = (1u << sh) - 1;
            sh = (sh > 11) ? sh - 11 : 0;
        }
        idxCut = lo2;
    }
    __syncthreads();

    // --- select exactly K, count buckets ---
    for (int i = t; i < NB_BUCKET; i += 1024) h[i] = 0;
    if (t == 0) sScalar = 0;
    __syncthreads();
    for (unsigned i = t; i < Nc; i += 1024) {
        unsigned k = candKey[i]; unsigned id = candIdx[i];
        if (k > T || (k == T && id <= idxCut)) {
            unsigned p = atomicAdd(&sScalar, 1u);
            if (p < K_TOP) {
                selKey[p] = k; selIdx[p] = id;
                atomicAdd(&h[id >> bshift], 1u);
            }
        }
    }
    __syncthreads();
    unsigned nSel = sScalar; if (nSel > K_TOP) nSel = K_TOP;

    // --- exclusive scan of bucket counts ---
    unsigned* bc = h;
    unsigned* bs = h + NB_BUCKET;
    { unsigned s = 0; for (int j = 0; j < 4; j++) s += bc[t * 4 + j]; part[t] = s; }
    __syncthreads();
    if (t < 32) { unsigned s = 0; for (int j = 0; j < 32; j++) s += part[t * 32 + j]; part2[t] = s; }
    __syncthreads();
    if (t == 0) { unsigned run = 0; for (int j = 0; j < 32; j++) { unsigned v = part2[j]; part2[j] = run; run += v; } }
    __syncthreads();
    if (t < 32) { unsigned run = part2[t]; for (int j = 0; j < 32; j++) { int id2 = t * 32 + j; unsigned v = part[id2]; part[id2] = run; run += v; } }
    __syncthreads();
    { unsigned run = part[t]; for (int j = 0; j < 4; j++) { bs[t * 4 + j] = run; run += bc[t * 4 + j]; } }
    __syncthreads();

    // --- scatter into bucket order (bs becomes cursor) ---
    for (unsigned g = t; g < nSel; g += 1024) {
        unsigned id = selIdx[g];
        unsigned b = id >> bshift;
        unsigned p = atomicAdd(&bs[b], 1u);
        if (p < K_TOP) { selKeyS[p] = selKey[g]; selIdxS[p] = id; }
    }
    __syncthreads();

    // --- per-bucket insertion sort by idx + emit ---
    for (int j = 0; j < 4; j++) {
        int b = t * 4 + j;
        unsigned cnt = bc[b];
        if (!cnt) continue;
        unsigned s = bs[b] - cnt;
        for (unsigned i = 0; i < cnt; i++) {
            unsigned mi = i, mv = selIdxS[s + i];
            for (unsigned q = i + 1; q < cnt; q++) {
                unsigned v = selIdxS[s + q];
                if (v < mv) { mv = v; mi = q; }
            }
            if (mi != i) {
                unsigned ti = selIdxS[s + i]; selIdxS[s + i] = selIdxS[s + mi]; selIdxS[s + mi] = ti;
                unsigned tk = selKeyS[s + i]; selKeyS[s + i] = selKeyS[s + mi]; selKeyS[s + mi] = tk;
            }
            out[s + i] = key2f(selKeyS[s + i]);
        }
    }
}

// ---- host launch --------------------------------------------------------
// ws words: hist[0..2047], ctrl[2048..2055], selKey[2056..7055], selIdx[7056..12055],
//           selKeyS[12056..17055], selIdxS[17056..22055], cand arrays from 24576.
extern "C" void kernel_launch(void* const* d_in, const int* in_sizes, int n_in,
                              void* d_out, int out_size, void* d_ws, size_t ws_size,
                              hipStream_t stream) {
    const float* x = (const float*)d_in[0];
    long n = in_sizes[0];
    float* out = (float*)d_out;
    unsigned* w = (unsigned*)d_ws;

    unsigned* hist    = w;
    unsigned* ctrl    = w + 2048;
    unsigned* selKey  = w + 2056;
    unsigned* selIdx  = w + 7056;
    unsigned* selKeyS = w + 12056;
    unsigned* selIdxS = w + 17056;
    const size_t CAND_BASE = 24576;
    size_t words = ws_size / 4;
    unsigned capC = 0;
    if (words > CAND_BASE + 64) {
        size_t c = (words - CAND_BASE) / 2;
        if (c > (size_t)(4u << 20)) c = (size_t)(4u << 20);
        capC = (unsigned)c;
    }
    unsigned* candKey = w + CAND_BASE;
    unsigned* candIdx = candKey + capC;

    int bshift = 0;
    while (((n - 1) >> bshift) >= NB_BUCKET) bshift++;

    hipMemsetAsync(d_ws, 0, 2056u * 4u + 32u, stream);

    long n4 = n / 4;
    k_sample<<<256, 256, 0, stream>>>((const float4*)x, n4, hist);
    k_findbin<<<1, 256, 0, stream>>>(hist, ctrl);
    k_compact<<<4096, 256, 0, stream>>>((const float4*)x, n4, n, x, ctrl,
                                        candKey, candIdx, capC);
    k_final<<<1, 1024, 0, stream>>>(candKey, candIdx, ctrl, capC,
                                    selKey, selIdx, selKeyS, selIdxS, out, n, bshift);
}